// Round 6
// baseline (5245.996 us; speedup 1.0000x reference)
//
#include <hip/hip_runtime.h>
#include <hip/hip_fp16.h>
#include <math.h>

#define H_DIM 180
#define W_DIM 360
#define CH    256
#define NHEAD 8
#define HD    32
#define MPIX  (H_DIM * W_DIM)   // 64800
#define KDIM  256

typedef _Float16 f16x8 __attribute__((ext_vector_type(8)));
typedef _Float16 h2    __attribute__((ext_vector_type(2)));
typedef float    f32x4 __attribute__((ext_vector_type(4)));

#if __has_builtin(__builtin_amdgcn_fdot2)
#define HAS_FDOT2 1
#else
#define HAS_FDOT2 0
#endif

__device__ __forceinline__ h2 pack2(float a, float b) {
#if __has_builtin(__builtin_amdgcn_cvt_pkrtz)
    return __builtin_bit_cast(h2, __builtin_amdgcn_cvt_pkrtz(a, b));
#else
    h2 r; r.x = (_Float16)a; r.y = (_Float16)b; return r;
#endif
}

// ---------------------------------------------------------------------------
// Kernel 0: fp32 -> fp16 conversions. y=0: X; y=1: w_qkv -> Wqt[768][256]
// (transposed); y=2: w_proj -> Wpt[256][256] (transposed).
// ---------------------------------------------------------------------------
__global__ __launch_bounds__(256)
void convert_kernel(const float* __restrict__ X, const float* __restrict__ Wq,
                    const float* __restrict__ Wp, _Float16* __restrict__ Xh,
                    _Float16* __restrict__ Wqt, _Float16* __restrict__ Wpt)
{
    const int tid = blockIdx.x * 256 + threadIdx.x;
    if (blockIdx.y == 0) {
        const float4* X4 = reinterpret_cast<const float4*>(X);
        const float4 a = X4[tid * 2];
        const float4 b = X4[tid * 2 + 1];
        uint4 o;
        o.x = __builtin_bit_cast(unsigned, pack2(a.x, a.y));
        o.y = __builtin_bit_cast(unsigned, pack2(a.z, a.w));
        o.z = __builtin_bit_cast(unsigned, pack2(b.x, b.y));
        o.w = __builtin_bit_cast(unsigned, pack2(b.z, b.w));
        reinterpret_cast<uint4*>(Xh)[tid] = o;
    } else if (blockIdx.y == 1) {
        if (tid < 768 * 256) {
            const int n = tid >> 8, k = tid & 255;
            Wqt[tid] = (_Float16)Wq[k * 768 + n];
        }
    } else {
        if (tid < 256 * 256) {
            const int n = tid >> 8, k = tid & 255;
            Wpt[tid] = (_Float16)Wp[k * 256 + n];
        }
    }
}

// ---------------------------------------------------------------------------
// MFMA fp16 GEMM, 128x128 tile, 4 waves (64x64 each), BK=64, K=256.
// MODE 0: qkv epilogue (bias, q-scale, scatter to [8][M][32] f16 q/k/v).
// MODE 1: proj epilogue (bias, fp32 out [M][NB]).
// ---------------------------------------------------------------------------
template<int NB, int MODE>
__global__ __launch_bounds__(256)
void mfma_gemm_kernel(const _Float16* __restrict__ A,
                      const _Float16* __restrict__ Bt,
                      const float* __restrict__ bias,
                      _Float16* __restrict__ qo, _Float16* __restrict__ ko,
                      _Float16* __restrict__ vo, float* __restrict__ outf,
                      int M)
{
    __shared__ __align__(16) _Float16 Alds[128 * 64];
    __shared__ __align__(16) _Float16 Blds[128 * 64];

    const int tid  = threadIdx.x;
    const int wid  = tid >> 6;
    const int lane = tid & 63;
    const int bn   = blockIdx.x * 128;
    const int bm   = blockIdx.y * 128;
    const int wr   = wid >> 1;
    const int wc   = wid & 1;

    f32x4 acc[4][4] = {};

    const int srow  = lane >> 3;
    const int sunit = (lane & 7) * 16;

    for (int k0 = 0; k0 < KDIM; k0 += 64) {
        #pragma unroll
        for (int i = 0; i < 4; ++i) {
            const int chunk = i * 4 + wid;
            const int row   = chunk * 8 + srow;
            int am = bm + row;
            am = (am < M) ? am : (M - 1);
            const char* asrc = (const char*)(A + (size_t)am * KDIM + k0) + sunit;
            __builtin_amdgcn_global_load_lds(
                (const __attribute__((address_space(1))) void*)asrc,
                (__attribute__((address_space(3))) void*)((char*)Alds + chunk * 1024),
                16, 0, 0);
            const char* bsrc = (const char*)(Bt + (size_t)(bn + row) * KDIM + k0) + sunit;
            __builtin_amdgcn_global_load_lds(
                (const __attribute__((address_space(1))) void*)bsrc,
                (__attribute__((address_space(3))) void*)((char*)Blds + chunk * 1024),
                16, 0, 0);
        }
        __syncthreads();
        #pragma unroll
        for (int kk = 0; kk < 64; kk += 32) {
            const int ko2 = kk + (lane >> 4) * 8;
            f16x8 af[4], bf[4];
            #pragma unroll
            for (int t = 0; t < 4; ++t) {
                af[t] = *(const f16x8*)&Alds[(wr * 64 + t * 16 + (lane & 15)) * 64 + ko2];
                bf[t] = *(const f16x8*)&Blds[(wc * 64 + t * 16 + (lane & 15)) * 64 + ko2];
            }
            #pragma unroll
            for (int fi = 0; fi < 4; ++fi)
                #pragma unroll
                for (int fj = 0; fj < 4; ++fj)
                    acc[fi][fj] = __builtin_amdgcn_mfma_f32_16x16x32_f16(
                        af[fi], bf[fj], acc[fi][fj], 0, 0, 0);
        }
        __syncthreads();
    }

    const int lc  = lane & 15;
    const int lrb = (lane >> 4) * 4;
    if (MODE == 0) {
        const float scale = 0.17677669529663687f;
        #pragma unroll
        for (int fj = 0; fj < 4; ++fj) {
            const int c = bn + wc * 64 + fj * 16 + lc;
            const float bv = bias[c];
            const int which = c >> 8;
            const int head  = (c >> 5) & 7;
            const int jd    = c & 31;
            _Float16* dst = (which == 0) ? qo : (which == 1) ? ko : vo;
            const float scl = (which == 0) ? scale : 1.0f;
            #pragma unroll
            for (int fi = 0; fi < 4; ++fi) {
                #pragma unroll
                for (int j = 0; j < 4; ++j) {
                    const int m = bm + wr * 64 + fi * 16 + lrb + j;
                    if (m < M)
                        dst[((size_t)head * M + m) * HD + jd] =
                            (_Float16)((acc[fi][fj][j] + bv) * scl);
                }
            }
        }
    } else {
        #pragma unroll
        for (int fj = 0; fj < 4; ++fj) {
            const int c = bn + wc * 64 + fj * 16 + lc;
            const float bv = bias[c];
            #pragma unroll
            for (int fi = 0; fi < 4; ++fi) {
                #pragma unroll
                for (int j = 0; j < 4; ++j) {
                    const int m = bm + wr * 64 + fi * 16 + lrb + j;
                    if (m < M)
                        outf[(size_t)m * NB + c] = acc[fi][fj][j] + bv;
                }
            }
        }
    }
}

// ---------------------------------------------------------------------------
// Attention, 2 queries/thread (vertical pair). Block = (head, 16h x 30w tile),
// 256 threads (240 active: 8 h-pairs x 30 w). Halo 22 rows x 36 cols, one
// 50.7 KB LDS buffer time-shared K then V. No max-subtraction (scores are
// O(1)); exp-weights stored packed half2 across the phases.
// ---------------------------------------------------------------------------
#define TROWS 16
#define TCOLS 30
#define KROWS2 22
#define KCOLS2 36
#define KUNITS2 (KROWS2 * KCOLS2 * 4)   // 3168 x 16B = 50688 B

__device__ __forceinline__ void stage_tile(const uint4* __restrict__ src,
                                           uint4* __restrict__ dst,
                                           int n, int r0, int w0, int tid)
{
    for (int u = tid; u < KUNITS2; u += 256) {
        const int row = u / (KCOLS2 * 4);
        const int rem = u - row * (KCOLS2 * 4);
        const int col = rem >> 2;
        const int t   = rem & 3;
        int grow = r0 + row;
        if (grow > H_DIM - 1) grow = H_DIM - 1;   // clamped rows never read
        int gcol = w0 - 3 + col;
        if (gcol < 0) gcol += W_DIM;
        else if (gcol >= W_DIM) gcol -= W_DIM;
        dst[(row * KCOLS2 + col) * 4 + (t ^ ((col >> 1) & 3))] =
            src[(((size_t)n * H_DIM + grow) * W_DIM + gcol) * 4 + t];
    }
}

__device__ __forceinline__ void dot2q(const uint4 kk, const h2* qa, const h2* qb,
                                      float& da, float& db)
{
    h2 k0 = __builtin_bit_cast(h2, kk.x);
    h2 k1 = __builtin_bit_cast(h2, kk.y);
    h2 k2 = __builtin_bit_cast(h2, kk.z);
    h2 k3 = __builtin_bit_cast(h2, kk.w);
#if HAS_FDOT2
    da = __builtin_amdgcn_fdot2(k0, qa[0], da, false);
    db = __builtin_amdgcn_fdot2(k0, qb[0], db, false);
    da = __builtin_amdgcn_fdot2(k1, qa[1], da, false);
    db = __builtin_amdgcn_fdot2(k1, qb[1], db, false);
    da = __builtin_amdgcn_fdot2(k2, qa[2], da, false);
    db = __builtin_amdgcn_fdot2(k2, qb[2], db, false);
    da = __builtin_amdgcn_fdot2(k3, qa[3], da, false);
    db = __builtin_amdgcn_fdot2(k3, qb[3], db, false);
#else
    da += (float)k0.x * (float)qa[0].x + (float)k0.y * (float)qa[0].y;
    db += (float)k0.x * (float)qb[0].x + (float)k0.y * (float)qb[0].y;
    da += (float)k1.x * (float)qa[1].x + (float)k1.y * (float)qa[1].y;
    db += (float)k1.x * (float)qb[1].x + (float)k1.y * (float)qb[1].y;
    da += (float)k2.x * (float)qa[2].x + (float)k2.y * (float)qa[2].y;
    db += (float)k2.x * (float)qb[2].x + (float)k2.y * (float)qb[2].y;
    da += (float)k3.x * (float)qa[3].x + (float)k3.y * (float)qa[3].y;
    db += (float)k3.x * (float)qb[3].x + (float)k3.y * (float)qb[3].y;
#endif
}

__global__ __launch_bounds__(256)
void natten_attn_kernel(const _Float16* __restrict__ q,   // [8][M][32]
                        const uint4* __restrict__ kb,
                        const uint4* __restrict__ vb,
                        const float* __restrict__ rpb,    // [8][13][13]
                        _Float16* __restrict__ outh)      // [M][256]
{
    __shared__ uint4 kvs[KUNITS2];
    __shared__ float rpbs[169];

    const int tid = threadIdx.x;
    const int n  = blockIdx.z;
    const int w0 = blockIdx.x * TCOLS;
    const int h0 = blockIdx.y * TROWS;

    int r0 = h0 - 3;
    if (r0 < 0) r0 = 0;
    if (r0 > H_DIM - 7) r0 = H_DIM - 7;

    if (tid < 169) rpbs[tid] = rpb[n * 169 + tid];

    // ---- phase 1: stage K ----
    stage_tile(kb, kvs, n, r0, w0, tid);
    __syncthreads();

    const int hl = tid / TCOLS;          // 0..8 (hl==8: tail threads, inactive)
    const int wl = tid - hl * TCOLS;     // 0..29
    const int w  = w0 + wl;
    const int hq0 = h0 + hl * 2;
    const int hq1 = hq0 + 1;
    const bool act = (hl < 8);
    const bool v0 = act && (hq0 < H_DIM);
    const bool v1 = act && (hq1 < H_DIM);

    int su = hq0 - 3;
    if (su < 0) su = 0;
    if (su > H_DIM - 7) su = H_DIM - 7;
    if (su > r0 + 14) su = r0 + 14;      // no-op for active threads; keeps
    int s1 = hq1 - 3;                    // inactive threads in-bounds
    if (s1 < 0) s1 = 0;
    if (s1 > H_DIM - 7) s1 = H_DIM - 7;
    if (s1 > su + 1) s1 = su + 1;
    const int dlt = s1 - su;             // 0 or 1
    const int ri0 = su - r0;             // 0..14
    const int bb0 = su - hq0 + 6;        // rpb row base for q0 at ri=0
    const int bb1 = su - hq1 + 6;

    // load q for both queries, packed half2 (16 VGPR each)
    const int ha0 = (hq0 < H_DIM) ? hq0 : H_DIM - 1;
    const int ha1 = (hq1 < H_DIM) ? hq1 : H_DIM - 1;
    h2 qh0[16], qh1[16];
    {
        const uint4* qp0 = reinterpret_cast<const uint4*>(
            q + ((size_t)n * MPIX + (size_t)ha0 * W_DIM + w) * HD);
        const uint4* qp1 = reinterpret_cast<const uint4*>(
            q + ((size_t)n * MPIX + (size_t)ha1 * W_DIM + w) * HD);
        #pragma unroll
        for (int t = 0; t < 4; ++t) {
            const uint4 a = qp0[t];
            qh0[t*4+0] = __builtin_bit_cast(h2, a.x);
            qh0[t*4+1] = __builtin_bit_cast(h2, a.y);
            qh0[t*4+2] = __builtin_bit_cast(h2, a.z);
            qh0[t*4+3] = __builtin_bit_cast(h2, a.w);
            const uint4 b = qp1[t];
            qh1[t*4+0] = __builtin_bit_cast(h2, b.x);
            qh1[t*4+1] = __builtin_bit_cast(h2, b.y);
            qh1[t*4+2] = __builtin_bit_cast(h2, b.z);
            qh1[t*4+3] = __builtin_bit_cast(h2, b.w);
        }
    }

    // QK over the 8-row x 7-col window union; exp without max-sub (|s| ~ O(1))
    h2 sc2[56];
    float l0 = 0.f, l1 = 0.f;
    #pragma unroll
    for (int ri = 0; ri < 8; ++ri) {
        const int rb = (ri0 + ri) * (KCOLS2 * 4);
        const bool in0 = (ri <= 6);
        const bool in1 = (ri >= dlt) && (ri <= dlt + 6);
        int b0 = bb0 + ri; b0 = b0 < 0 ? 0 : (b0 > 12 ? 12 : b0);
        int b1 = bb1 + ri; b1 = b1 < 0 ? 0 : (b1 > 12 ? 12 : b1);
        const float* rp0 = &rpbs[b0 * 13 + 3];
        const float* rp1 = &rpbs[b1 * 13 + 3];
        #pragma unroll
        for (int oj = 0; oj < 7; ++oj) {
            const int cl = wl + oj;
            const int base = rb + cl * 4;
            const int sw = (cl >> 1) & 3;
            float d0 = rp0[oj];
            float d1 = rp1[oj];
            dot2q(kvs[base + (0 ^ sw)], qh0 + 0, qh1 + 0, d0, d1);
            dot2q(kvs[base + (1 ^ sw)], qh0 + 4, qh1 + 4, d0, d1);
            dot2q(kvs[base + (2 ^ sw)], qh0 + 8, qh1 + 8, d0, d1);
            dot2q(kvs[base + (3 ^ sw)], qh0 + 12, qh1 + 12, d0, d1);
            float e0 = __expf(d0);
            float e1 = __expf(d1);
            e0 = (v0 && in0) ? e0 : 0.f;
            e1 = (v1 && in1) ? e1 : 0.f;
            l0 += e0; l1 += e1;
            sc2[ri * 7 + oj] = pack2(e0, e1);
        }
    }
    __syncthreads();

    // ---- phase 2: stage V into the same buffer ----
    stage_tile(vb, kvs, n, r0, w0, tid);
    __syncthreads();

    if (!act) return;   // no barriers past this point

    float a0[32], a1[32];
    #pragma unroll
    for (int t = 0; t < 32; ++t) { a0[t] = 0.f; a1[t] = 0.f; }

    #pragma unroll
    for (int ri = 0; ri < 8; ++ri) {
        const int rb = (ri0 + ri) * (KCOLS2 * 4);
        #pragma unroll
        for (int oj = 0; oj < 7; ++oj) {
            const int cl = wl + oj;
            const int base = rb + cl * 4;
            const int sw = (cl >> 1) & 3;
            const h2 ee = sc2[ri * 7 + oj];
            const float e0 = (float)ee.x;
            const float e1 = (float)ee.y;
            #pragma unroll
            for (int t = 0; t < 4; ++t) {
                const uint4 vv = kvs[base + (t ^ sw)];
                h2 p0 = __builtin_bit_cast(h2, vv.x);
                h2 p1 = __builtin_bit_cast(h2, vv.y);
                h2 p2 = __builtin_bit_cast(h2, vv.z);
                h2 p3 = __builtin_bit_cast(h2, vv.w);
                a0[t*8+0] += e0 * (float)p0.x; a0[t*8+1] += e0 * (float)p0.y;
                a0[t*8+2] += e0 * (float)p1.x; a0[t*8+3] += e0 * (float)p1.y;
                a0[t*8+4] += e0 * (float)p2.x; a0[t*8+5] += e0 * (float)p2.y;
                a0[t*8+6] += e0 * (float)p3.x; a0[t*8+7] += e0 * (float)p3.y;
                a1[t*8+0] += e1 * (float)p0.x; a1[t*8+1] += e1 * (float)p0.y;
                a1[t*8+2] += e1 * (float)p1.x; a1[t*8+3] += e1 * (float)p1.y;
                a1[t*8+4] += e1 * (float)p2.x; a1[t*8+5] += e1 * (float)p2.y;
                a1[t*8+6] += e1 * (float)p3.x; a1[t*8+7] += e1 * (float)p3.y;
            }
        }
    }

    if (v0) {
        const float inv = 1.f / l0;
        uint4 o[4];
        #pragma unroll
        for (int t = 0; t < 4; ++t) {
            o[t].x = __builtin_bit_cast(unsigned, pack2(a0[t*8+0]*inv, a0[t*8+1]*inv));
            o[t].y = __builtin_bit_cast(unsigned, pack2(a0[t*8+2]*inv, a0[t*8+3]*inv));
            o[t].z = __builtin_bit_cast(unsigned, pack2(a0[t*8+4]*inv, a0[t*8+5]*inv));
            o[t].w = __builtin_bit_cast(unsigned, pack2(a0[t*8+6]*inv, a0[t*8+7]*inv));
        }
        uint4* op = reinterpret_cast<uint4*>(
            outh + (((size_t)hq0 * W_DIM + w) * CH + n * HD));
        #pragma unroll
        for (int t = 0; t < 4; ++t) op[t] = o[t];
    }
    if (v1) {
        const float inv = 1.f / l1;
        uint4 o[4];
        #pragma unroll
        for (int t = 0; t < 4; ++t) {
            o[t].x = __builtin_bit_cast(unsigned, pack2(a1[t*8+0]*inv, a1[t*8+1]*inv));
            o[t].y = __builtin_bit_cast(unsigned, pack2(a1[t*8+2]*inv, a1[t*8+3]*inv));
            o[t].z = __builtin_bit_cast(unsigned, pack2(a1[t*8+4]*inv, a1[t*8+5]*inv));
            o[t].w = __builtin_bit_cast(unsigned, pack2(a1[t*8+6]*inv, a1[t*8+7]*inv));
        }
        uint4* op = reinterpret_cast<uint4*>(
            outh + (((size_t)hq1 * W_DIM + w) * CH + n * HD));
        #pragma unroll
        for (int t = 0; t < 4; ++t) op[t] = o[t];
    }
}

// ---------------------------------------------------------------------------
extern "C" void kernel_launch(void* const* d_in, const int* in_sizes, int n_in,
                              void* d_out, int out_size, void* d_ws, size_t ws_size,
                              hipStream_t stream)
{
    const float* x      = (const float*)d_in[0];
    const float* w_qkv  = (const float*)d_in[1];
    const float* b_qkv  = (const float*)d_in[2];
    const float* rpb    = (const float*)d_in[3];
    const float* w_proj = (const float*)d_in[4];
    const float* b_proj = (const float*)d_in[5];
    float* out = (float*)d_out;

    const int M = MPIX;
    const size_t nelem = (size_t)M * KDIM;

    _Float16* Xh  = (_Float16*)d_ws;
    _Float16* Wqt = Xh  + nelem;
    _Float16* Wpt = Wqt + 768 * 256;
    _Float16* qb  = Wpt + 256 * 256;
    _Float16* kb  = qb  + nelem;
    _Float16* vb  = kb  + nelem;
    _Float16* ah  = vb  + nelem;

    const size_t need = (5 * nelem + 768 * 256 + 256 * 256) * sizeof(_Float16);
    if (ws_size < need) return;

    dim3 blk(256);
    convert_kernel<<<dim3(8100, 3), blk, 0, stream>>>(x, w_qkv, w_proj, Xh, Wqt, Wpt);

    mfma_gemm_kernel<768, 0><<<dim3(6, 507), blk, 0, stream>>>(
        Xh, Wqt, b_qkv, qb, kb, vb, nullptr, M);

    natten_attn_kernel<<<dim3(W_DIM / TCOLS, (H_DIM + TROWS - 1) / TROWS, NHEAD),
                         blk, 0, stream>>>(
        qb, (const uint4*)kb, (const uint4*)vb, rpb, ah);

    mfma_gemm_kernel<256, 1><<<dim3(2, 507), blk, 0, stream>>>(
        ah, Wpt, b_proj, nullptr, nullptr, nullptr, out, M);
}

// Round 7
// 709.646 us; speedup vs baseline: 7.3924x; 7.3924x over previous
//
#include <hip/hip_runtime.h>
#include <hip/hip_fp16.h>
#include <math.h>

#define H_DIM 180
#define W_DIM 360
#define CH    256
#define NHEAD 8
#define HD    32
#define MPIX  (H_DIM * W_DIM)   // 64800
#define KDIM  256

typedef _Float16 f16x8 __attribute__((ext_vector_type(8)));
typedef _Float16 h2    __attribute__((ext_vector_type(2)));
typedef float    f32x4 __attribute__((ext_vector_type(4)));

#if __has_builtin(__builtin_amdgcn_fdot2)
#define HAS_FDOT2 1
#else
#define HAS_FDOT2 0
#endif

__device__ __forceinline__ h2 pack2(float a, float b) {
#if __has_builtin(__builtin_amdgcn_cvt_pkrtz)
    return __builtin_bit_cast(h2, __builtin_amdgcn_cvt_pkrtz(a, b));
#else
    h2 r; r.x = (_Float16)a; r.y = (_Float16)b; return r;
#endif
}

// ---------------------------------------------------------------------------
// Kernel 0: fp32 -> fp16 conversions. y=0: X; y=1: w_qkv -> Wqt[768][256]
// (transposed); y=2: w_proj -> Wpt[256][256] (transposed).
// ---------------------------------------------------------------------------
__global__ __launch_bounds__(256)
void convert_kernel(const float* __restrict__ X, const float* __restrict__ Wq,
                    const float* __restrict__ Wp, _Float16* __restrict__ Xh,
                    _Float16* __restrict__ Wqt, _Float16* __restrict__ Wpt)
{
    const int tid = blockIdx.x * 256 + threadIdx.x;
    if (blockIdx.y == 0) {
        const float4* X4 = reinterpret_cast<const float4*>(X);
        const float4 a = X4[tid * 2];
        const float4 b = X4[tid * 2 + 1];
        uint4 o;
        o.x = __builtin_bit_cast(unsigned, pack2(a.x, a.y));
        o.y = __builtin_bit_cast(unsigned, pack2(a.z, a.w));
        o.z = __builtin_bit_cast(unsigned, pack2(b.x, b.y));
        o.w = __builtin_bit_cast(unsigned, pack2(b.z, b.w));
        reinterpret_cast<uint4*>(Xh)[tid] = o;
    } else if (blockIdx.y == 1) {
        if (tid < 768 * 256) {
            const int n = tid >> 8, k = tid & 255;
            Wqt[tid] = (_Float16)Wq[k * 768 + n];
        }
    } else {
        if (tid < 256 * 256) {
            const int n = tid >> 8, k = tid & 255;
            Wpt[tid] = (_Float16)Wp[k * 256 + n];
        }
    }
}

// ---------------------------------------------------------------------------
// MFMA fp16 GEMM, 128x128 tile, 4 waves (64x64 each), BK=64, K=256.
// MODE 0: qkv epilogue (bias, q-scale, scatter to [8][M][32] f16 q/k/v).
// MODE 1: proj epilogue (bias, fp32 out [M][NB]).
// ---------------------------------------------------------------------------
template<int NB, int MODE>
__global__ __launch_bounds__(256)
void mfma_gemm_kernel(const _Float16* __restrict__ A,
                      const _Float16* __restrict__ Bt,
                      const float* __restrict__ bias,
                      _Float16* __restrict__ qo, _Float16* __restrict__ ko,
                      _Float16* __restrict__ vo, float* __restrict__ outf,
                      int M)
{
    __shared__ __align__(16) _Float16 Alds[128 * 64];
    __shared__ __align__(16) _Float16 Blds[128 * 64];

    const int tid  = threadIdx.x;
    const int wid  = tid >> 6;
    const int lane = tid & 63;
    const int bn   = blockIdx.x * 128;
    const int bm   = blockIdx.y * 128;
    const int wr   = wid >> 1;
    const int wc   = wid & 1;

    f32x4 acc[4][4] = {};

    const int srow  = lane >> 3;
    const int sunit = (lane & 7) * 16;

    for (int k0 = 0; k0 < KDIM; k0 += 64) {
        #pragma unroll
        for (int i = 0; i < 4; ++i) {
            const int chunk = i * 4 + wid;
            const int row   = chunk * 8 + srow;
            int am = bm + row;
            am = (am < M) ? am : (M - 1);
            const char* asrc = (const char*)(A + (size_t)am * KDIM + k0) + sunit;
            __builtin_amdgcn_global_load_lds(
                (const __attribute__((address_space(1))) void*)asrc,
                (__attribute__((address_space(3))) void*)((char*)Alds + chunk * 1024),
                16, 0, 0);
            const char* bsrc = (const char*)(Bt + (size_t)(bn + row) * KDIM + k0) + sunit;
            __builtin_amdgcn_global_load_lds(
                (const __attribute__((address_space(1))) void*)bsrc,
                (__attribute__((address_space(3))) void*)((char*)Blds + chunk * 1024),
                16, 0, 0);
        }
        __syncthreads();
        #pragma unroll
        for (int kk = 0; kk < 64; kk += 32) {
            const int ko2 = kk + (lane >> 4) * 8;
            f16x8 af[4], bf[4];
            #pragma unroll
            for (int t = 0; t < 4; ++t) {
                af[t] = *(const f16x8*)&Alds[(wr * 64 + t * 16 + (lane & 15)) * 64 + ko2];
                bf[t] = *(const f16x8*)&Blds[(wc * 64 + t * 16 + (lane & 15)) * 64 + ko2];
            }
            #pragma unroll
            for (int fi = 0; fi < 4; ++fi)
                #pragma unroll
                for (int fj = 0; fj < 4; ++fj)
                    acc[fi][fj] = __builtin_amdgcn_mfma_f32_16x16x32_f16(
                        af[fi], bf[fj], acc[fi][fj], 0, 0, 0);
        }
        __syncthreads();
    }

    const int lc  = lane & 15;
    const int lrb = (lane >> 4) * 4;
    if (MODE == 0) {
        const float scale = 0.17677669529663687f;
        #pragma unroll
        for (int fj = 0; fj < 4; ++fj) {
            const int c = bn + wc * 64 + fj * 16 + lc;
            const float bv = bias[c];
            const int which = c >> 8;
            const int head  = (c >> 5) & 7;
            const int jd    = c & 31;
            _Float16* dst = (which == 0) ? qo : (which == 1) ? ko : vo;
            const float scl = (which == 0) ? scale : 1.0f;
            #pragma unroll
            for (int fi = 0; fi < 4; ++fi) {
                #pragma unroll
                for (int j = 0; j < 4; ++j) {
                    const int m = bm + wr * 64 + fi * 16 + lrb + j;
                    if (m < M)
                        dst[((size_t)head * M + m) * HD + jd] =
                            (_Float16)((acc[fi][fj][j] + bv) * scl);
                }
            }
        }
    } else {
        #pragma unroll
        for (int fj = 0; fj < 4; ++fj) {
            const int c = bn + wc * 64 + fj * 16 + lc;
            const float bv = bias[c];
            #pragma unroll
            for (int fi = 0; fi < 4; ++fi) {
                #pragma unroll
                for (int j = 0; j < 4; ++j) {
                    const int m = bm + wr * 64 + fi * 16 + lrb + j;
                    if (m < M)
                        outf[(size_t)m * NB + c] = acc[fi][fj][j] + bv;
                }
            }
        }
    }
}

// ---------------------------------------------------------------------------
// Attention, 2 HORIZONTALLY adjacent queries per thread (w, w+1; same h).
// Block = (head, 8h x 60w tile): 240 of 256 threads active (8 h x 30 pairs).
// Both queries share the same 7-row window; col union = 8 cols -> 56
// neighbors, each K/V 16B unit read ONCE and used by both queries.
// Halo 14 rows x 66 cols fp16 = 59.1 KB, single buffer time-shared K -> V.
// 3-bit XOR swizzle handles the stride-2 column access of paired threads.
// sched_barrier(0) every 2 neighbors bounds ds_read hoisting (round-6 spill).
// ---------------------------------------------------------------------------
#define TROWS 8
#define TPAIR 30
#define KROWS3 14
#define KCOLS3 66
#define KUNITS3 (KROWS3 * KCOLS3 * 4)   // 3696 x 16B = 59136 B

__device__ __forceinline__ int swz(int col, int t) {
    return (col * 4 + t) ^ ((col >> 1) & 7);
}

__device__ __forceinline__ void stage_tile3(const uint4* __restrict__ src,
                                            uint4* __restrict__ dst,
                                            int n, int r0, int w0, int tid)
{
    for (int u = tid; u < KUNITS3; u += 256) {
        const int row = u / (KCOLS3 * 4);
        const int rem = u - row * (KCOLS3 * 4);
        const int col = rem >> 2;
        const int t   = rem & 3;
        int grow = r0 + row;
        if (grow > H_DIM - 1) grow = H_DIM - 1;   // clamped rows never read
        int gcol = w0 - 3 + col;
        if (gcol < 0) gcol += W_DIM;
        else if (gcol >= W_DIM) gcol -= W_DIM;
        dst[row * (KCOLS3 * 4) + swz(col, t)] =
            src[(((size_t)n * H_DIM + grow) * W_DIM + gcol) * 4 + t];
    }
}

__device__ __forceinline__ void dot2q(const uint4 kk, const h2* qa, const h2* qb,
                                      float& da, float& db)
{
    h2 k0 = __builtin_bit_cast(h2, kk.x);
    h2 k1 = __builtin_bit_cast(h2, kk.y);
    h2 k2 = __builtin_bit_cast(h2, kk.z);
    h2 k3 = __builtin_bit_cast(h2, kk.w);
#if HAS_FDOT2
    da = __builtin_amdgcn_fdot2(k0, qa[0], da, false);
    db = __builtin_amdgcn_fdot2(k0, qb[0], db, false);
    da = __builtin_amdgcn_fdot2(k1, qa[1], da, false);
    db = __builtin_amdgcn_fdot2(k1, qb[1], db, false);
    da = __builtin_amdgcn_fdot2(k2, qa[2], da, false);
    db = __builtin_amdgcn_fdot2(k2, qb[2], db, false);
    da = __builtin_amdgcn_fdot2(k3, qa[3], da, false);
    db = __builtin_amdgcn_fdot2(k3, qb[3], db, false);
#else
    da += (float)k0.x * (float)qa[0].x + (float)k0.y * (float)qa[0].y;
    db += (float)k0.x * (float)qb[0].x + (float)k0.y * (float)qb[0].y;
    da += (float)k1.x * (float)qa[1].x + (float)k1.y * (float)qa[1].y;
    db += (float)k1.x * (float)qb[1].x + (float)k1.y * (float)qb[1].y;
    da += (float)k2.x * (float)qa[2].x + (float)k2.y * (float)qa[2].y;
    db += (float)k2.x * (float)qb[2].x + (float)k2.y * (float)qb[2].y;
    da += (float)k3.x * (float)qa[3].x + (float)k3.y * (float)qa[3].y;
    db += (float)k3.x * (float)qb[3].x + (float)k3.y * (float)qb[3].y;
#endif
}

__global__ __launch_bounds__(256)
void natten_attn_kernel(const _Float16* __restrict__ q,   // [8][M][32]
                        const uint4* __restrict__ kb,
                        const uint4* __restrict__ vb,
                        const float* __restrict__ rpb,    // [8][13][13]
                        _Float16* __restrict__ outh)      // [M][256]
{
    __shared__ uint4 kvs[KUNITS3];
    __shared__ float rpbs[169];

    const int tid = threadIdx.x;
    const int n  = blockIdx.z;
    const int w0 = blockIdx.x * (TPAIR * 2);
    const int h0 = blockIdx.y * TROWS;

    int r0 = h0 - 3;
    if (r0 < 0) r0 = 0;
    if (r0 > H_DIM - 7) r0 = H_DIM - 7;

    if (tid < 169) rpbs[tid] = rpb[n * 169 + tid];

    // ---- phase 1: stage K ----
    stage_tile3(kb, kvs, n, r0, w0, tid);
    __syncthreads();

    const int hl = tid / TPAIR;          // 0..8 (hl==8: 16 tail threads)
    const int pl = tid - hl * TPAIR;     // 0..29
    const bool act = (hl < 8);
    const int h  = h0 + hl;
    const int wq = w0 + 2 * pl;          // query 0 at wq, query 1 at wq+1
    const bool v0 = act && (h < H_DIM);
    const bool v1 = v0;                  // w always in-range (360 = 6*60)

    int su = h - 3;
    if (su < 0) su = 0;
    if (su > H_DIM - 7) su = H_DIM - 7;
    int ri0 = su - r0;
    if (ri0 > 7) ri0 = 7;                // only inactive threads hit this
    int rh0 = su - h + 6;
    if (rh0 < 0) rh0 = 0;                // only inactive threads hit this

    // q for both queries, packed half2 (16 VGPR each)
    const int ha = (h < H_DIM) ? h : H_DIM - 1;
    h2 qh0[16], qh1[16];
    {
        const uint4* qp = reinterpret_cast<const uint4*>(
            q + ((size_t)n * MPIX + (size_t)ha * W_DIM + wq) * HD);
        #pragma unroll
        for (int t = 0; t < 4; ++t) {
            const uint4 a = qp[t];
            qh0[t*4+0] = __builtin_bit_cast(h2, a.x);
            qh0[t*4+1] = __builtin_bit_cast(h2, a.y);
            qh0[t*4+2] = __builtin_bit_cast(h2, a.z);
            qh0[t*4+3] = __builtin_bit_cast(h2, a.w);
            const uint4 b = qp[4 + t];
            qh1[t*4+0] = __builtin_bit_cast(h2, b.x);
            qh1[t*4+1] = __builtin_bit_cast(h2, b.y);
            qh1[t*4+2] = __builtin_bit_cast(h2, b.z);
            qh1[t*4+3] = __builtin_bit_cast(h2, b.w);
        }
    }

    // QK over 7 rows x 8 union cols; exp without max-sub (|s| ~ O(1))
    h2 sc2[56];
    float l0 = 0.f, l1 = 0.f;
    #pragma unroll
    for (int ri = 0; ri < 7; ++ri) {
        const int rbase = (ri0 + ri) * (KCOLS3 * 4);
        const float* rpr = &rpbs[(rh0 + ri) * 13];
        #pragma unroll
        for (int ojp = 0; ojp < 4; ++ojp) {
            #pragma unroll
            for (int uu = 0; uu < 2; ++uu) {
                const int oj = ojp * 2 + uu;
                const int cl = 2 * pl + oj;
                float d0 = rpr[3 + oj];      // junk at oj==7, masked below
                float d1 = rpr[2 + oj];      // junk at oj==0, masked below
                dot2q(kvs[rbase + swz(cl, 0)], qh0 + 0,  qh1 + 0,  d0, d1);
                dot2q(kvs[rbase + swz(cl, 1)], qh0 + 4,  qh1 + 4,  d0, d1);
                dot2q(kvs[rbase + swz(cl, 2)], qh0 + 8,  qh1 + 8,  d0, d1);
                dot2q(kvs[rbase + swz(cl, 3)], qh0 + 12, qh1 + 12, d0, d1);
                float e0 = (v0 && oj <= 6) ? __expf(d0) : 0.f;
                float e1 = (v1 && oj >= 1) ? __expf(d1) : 0.f;
                l0 += e0; l1 += e1;
                sc2[ri * 8 + oj] = pack2(e0, e1);
            }
            __builtin_amdgcn_sched_barrier(0);
        }
    }
    __syncthreads();

    // ---- phase 2: stage V into the same buffer ----
    stage_tile3(vb, kvs, n, r0, w0, tid);
    __syncthreads();

    if (!act) return;   // no barriers past this point

    float a0[32], a1[32];
    #pragma unroll
    for (int t = 0; t < 32; ++t) { a0[t] = 0.f; a1[t] = 0.f; }

    #pragma unroll
    for (int ri = 0; ri < 7; ++ri) {
        const int rbase = (ri0 + ri) * (KCOLS3 * 4);
        #pragma unroll
        for (int ojp = 0; ojp < 4; ++ojp) {
            #pragma unroll
            for (int uu = 0; uu < 2; ++uu) {
                const int oj = ojp * 2 + uu;
                const int cl = 2 * pl + oj;
                const h2 ee = sc2[ri * 8 + oj];
                const float e0 = (float)ee.x;
                const float e1 = (float)ee.y;
                #pragma unroll
                for (int t = 0; t < 4; ++t) {
                    const uint4 vv = kvs[rbase + swz(cl, t)];
                    h2 p0 = __builtin_bit_cast(h2, vv.x);
                    h2 p1 = __builtin_bit_cast(h2, vv.y);
                    h2 p2 = __builtin_bit_cast(h2, vv.z);
                    h2 p3 = __builtin_bit_cast(h2, vv.w);
                    a0[t*8+0] += e0 * (float)p0.x; a0[t*8+1] += e0 * (float)p0.y;
                    a0[t*8+2] += e0 * (float)p1.x; a0[t*8+3] += e0 * (float)p1.y;
                    a0[t*8+4] += e0 * (float)p2.x; a0[t*8+5] += e0 * (float)p2.y;
                    a0[t*8+6] += e0 * (float)p3.x; a0[t*8+7] += e0 * (float)p3.y;
                    a1[t*8+0] += e1 * (float)p0.x; a1[t*8+1] += e1 * (float)p0.y;
                    a1[t*8+2] += e1 * (float)p1.x; a1[t*8+3] += e1 * (float)p1.y;
                    a1[t*8+4] += e1 * (float)p2.x; a1[t*8+5] += e1 * (float)p2.y;
                    a1[t*8+6] += e1 * (float)p3.x; a1[t*8+7] += e1 * (float)p3.y;
                }
            }
            __builtin_amdgcn_sched_barrier(0);
        }
    }

    if (v0) {
        const float inv0 = 1.f / l0;
        const float inv1 = 1.f / l1;
        uint4 o[8];
        #pragma unroll
        for (int t = 0; t < 4; ++t) {
            o[t].x = __builtin_bit_cast(unsigned, pack2(a0[t*8+0]*inv0, a0[t*8+1]*inv0));
            o[t].y = __builtin_bit_cast(unsigned, pack2(a0[t*8+2]*inv0, a0[t*8+3]*inv0));
            o[t].z = __builtin_bit_cast(unsigned, pack2(a0[t*8+4]*inv0, a0[t*8+5]*inv0));
            o[t].w = __builtin_bit_cast(unsigned, pack2(a0[t*8+6]*inv0, a0[t*8+7]*inv0));
            o[4+t].x = __builtin_bit_cast(unsigned, pack2(a1[t*8+0]*inv1, a1[t*8+1]*inv1));
            o[4+t].y = __builtin_bit_cast(unsigned, pack2(a1[t*8+2]*inv1, a1[t*8+3]*inv1));
            o[4+t].z = __builtin_bit_cast(unsigned, pack2(a1[t*8+4]*inv1, a1[t*8+5]*inv1));
            o[4+t].w = __builtin_bit_cast(unsigned, pack2(a1[t*8+6]*inv1, a1[t*8+7]*inv1));
        }
        uint4* op0 = reinterpret_cast<uint4*>(
            outh + (((size_t)h * W_DIM + wq) * CH + n * HD));
        uint4* op1 = reinterpret_cast<uint4*>(
            outh + (((size_t)h * W_DIM + wq + 1) * CH + n * HD));
        #pragma unroll
        for (int t = 0; t < 4; ++t) op0[t] = o[t];
        #pragma unroll
        for (int t = 0; t < 4; ++t) op1[t] = o[4 + t];
    }
}

// ---------------------------------------------------------------------------
extern "C" void kernel_launch(void* const* d_in, const int* in_sizes, int n_in,
                              void* d_out, int out_size, void* d_ws, size_t ws_size,
                              hipStream_t stream)
{
    const float* x      = (const float*)d_in[0];
    const float* w_qkv  = (const float*)d_in[1];
    const float* b_qkv  = (const float*)d_in[2];
    const float* rpb    = (const float*)d_in[3];
    const float* w_proj = (const float*)d_in[4];
    const float* b_proj = (const float*)d_in[5];
    float* out = (float*)d_out;

    const int M = MPIX;
    const size_t nelem = (size_t)M * KDIM;

    _Float16* Xh  = (_Float16*)d_ws;
    _Float16* Wqt = Xh  + nelem;
    _Float16* Wpt = Wqt + 768 * 256;
    _Float16* qb  = Wpt + 256 * 256;
    _Float16* kb  = qb  + nelem;
    _Float16* vb  = kb  + nelem;
    _Float16* ah  = vb  + nelem;

    const size_t need = (5 * nelem + 768 * 256 + 256 * 256) * sizeof(_Float16);
    if (ws_size < need) return;

    dim3 blk(256);
    convert_kernel<<<dim3(8100, 3), blk, 0, stream>>>(x, w_qkv, w_proj, Xh, Wqt, Wpt);

    mfma_gemm_kernel<768, 0><<<dim3(6, 507), blk, 0, stream>>>(
        Xh, Wqt, b_qkv, qb, kb, vb, nullptr, M);

    natten_attn_kernel<<<dim3(W_DIM / (TPAIR * 2), (H_DIM + TROWS - 1) / TROWS, NHEAD),
                         blk, 0, stream>>>(
        qb, (const uint4*)kb, (const uint4*)vb, rpb, ah);

    mfma_gemm_kernel<256, 1><<<dim3(2, 507), blk, 0, stream>>>(
        ah, Wpt, b_proj, nullptr, nullptr, nullptr, out, M);
}

// Round 8
// 221.609 us; speedup vs baseline: 23.6723x; 3.2022x over previous
//
#include <hip/hip_runtime.h>
#include <hip/hip_fp16.h>
#include <math.h>

#define H_DIM 180
#define W_DIM 360
#define CH    256
#define NHEAD 8
#define HD    32
#define MPIX  (H_DIM * W_DIM)   // 64800
#define KDIM  256

typedef _Float16 f16x8 __attribute__((ext_vector_type(8)));
typedef _Float16 h2    __attribute__((ext_vector_type(2)));
typedef float    f32x4 __attribute__((ext_vector_type(4)));

#if __has_builtin(__builtin_amdgcn_fdot2)
#define HAS_FDOT2 1
#else
#define HAS_FDOT2 0
#endif

__device__ __forceinline__ h2 pack2(float a, float b) {
#if __has_builtin(__builtin_amdgcn_cvt_pkrtz)
    return __builtin_bit_cast(h2, __builtin_amdgcn_cvt_pkrtz(a, b));
#else
    h2 r; r.x = (_Float16)a; r.y = (_Float16)b; return r;
#endif
}

// ---------------------------------------------------------------------------
// Kernel 0: fp32 -> fp16 conversions. y=0: X; y=1: w_qkv -> Wqt[768][256]
// (transposed); y=2: w_proj -> Wpt[256][256] (transposed).
// ---------------------------------------------------------------------------
__global__ __launch_bounds__(256)
void convert_kernel(const float* __restrict__ X, const float* __restrict__ Wq,
                    const float* __restrict__ Wp, _Float16* __restrict__ Xh,
                    _Float16* __restrict__ Wqt, _Float16* __restrict__ Wpt)
{
    const int tid = blockIdx.x * 256 + threadIdx.x;
    if (blockIdx.y == 0) {
        const float4* X4 = reinterpret_cast<const float4*>(X);
        const float4 a = X4[tid * 2];
        const float4 b = X4[tid * 2 + 1];
        uint4 o;
        o.x = __builtin_bit_cast(unsigned, pack2(a.x, a.y));
        o.y = __builtin_bit_cast(unsigned, pack2(a.z, a.w));
        o.z = __builtin_bit_cast(unsigned, pack2(b.x, b.y));
        o.w = __builtin_bit_cast(unsigned, pack2(b.z, b.w));
        reinterpret_cast<uint4*>(Xh)[tid] = o;
    } else if (blockIdx.y == 1) {
        if (tid < 768 * 256) {
            const int n = tid >> 8, k = tid & 255;
            Wqt[tid] = (_Float16)Wq[k * 768 + n];
        }
    } else {
        if (tid < 256 * 256) {
            const int n = tid >> 8, k = tid & 255;
            Wpt[tid] = (_Float16)Wp[k * 256 + n];
        }
    }
}

// ---------------------------------------------------------------------------
// MFMA fp16 GEMM, 128x128 tile, 4 waves (64x64 each), BK=64, K=256.
// MODE 0: qkv epilogue -> coalesced fp16 scatter via per-wave LDS transpose.
// MODE 1: proj epilogue (bias, fp32 out [M][NB]).
// ---------------------------------------------------------------------------
template<int NB, int MODE>
__global__ __launch_bounds__(256)
void mfma_gemm_kernel(const _Float16* __restrict__ A,
                      const _Float16* __restrict__ Bt,
                      const float* __restrict__ bias,
                      _Float16* __restrict__ qo, _Float16* __restrict__ ko,
                      _Float16* __restrict__ vo, float* __restrict__ outf,
                      int M)
{
    __shared__ __align__(16) _Float16 Alds[128 * 64];
    __shared__ __align__(16) _Float16 Blds[128 * 64];

    const int tid  = threadIdx.x;
    const int wid  = tid >> 6;
    const int lane = tid & 63;
    const int bn   = blockIdx.x * 128;
    const int bm   = blockIdx.y * 128;
    const int wr   = wid >> 1;
    const int wc   = wid & 1;

    f32x4 acc[4][4] = {};

    const int srow  = lane >> 3;
    const int sunit = (lane & 7) * 16;

    for (int k0 = 0; k0 < KDIM; k0 += 64) {
        #pragma unroll
        for (int i = 0; i < 4; ++i) {
            const int chunk = i * 4 + wid;
            const int row   = chunk * 8 + srow;
            int am = bm + row;
            am = (am < M) ? am : (M - 1);
            const char* asrc = (const char*)(A + (size_t)am * KDIM + k0) + sunit;
            __builtin_amdgcn_global_load_lds(
                (const __attribute__((address_space(1))) void*)asrc,
                (__attribute__((address_space(3))) void*)((char*)Alds + chunk * 1024),
                16, 0, 0);
            const char* bsrc = (const char*)(Bt + (size_t)(bn + row) * KDIM + k0) + sunit;
            __builtin_amdgcn_global_load_lds(
                (const __attribute__((address_space(1))) void*)bsrc,
                (__attribute__((address_space(3))) void*)((char*)Blds + chunk * 1024),
                16, 0, 0);
        }
        __syncthreads();
        #pragma unroll
        for (int kk = 0; kk < 64; kk += 32) {
            const int ko2 = kk + (lane >> 4) * 8;
            f16x8 af[4], bf[4];
            #pragma unroll
            for (int t = 0; t < 4; ++t) {
                af[t] = *(const f16x8*)&Alds[(wr * 64 + t * 16 + (lane & 15)) * 64 + ko2];
                bf[t] = *(const f16x8*)&Blds[(wc * 64 + t * 16 + (lane & 15)) * 64 + ko2];
            }
            #pragma unroll
            for (int fi = 0; fi < 4; ++fi)
                #pragma unroll
                for (int fj = 0; fj < 4; ++fj)
                    acc[fi][fj] = __builtin_amdgcn_mfma_f32_16x16x32_f16(
                        af[fi], bf[fj], acc[fi][fj], 0, 0, 0);
        }
        __syncthreads();
    }

    // epilogue — C/D layout: col = lane&15, row = (lane>>4)*4 + j
    const int lc  = lane & 15;
    const int lrb = (lane >> 4) * 4;
    if (MODE == 0) {
        // Coalesced store path: per (fi, fj-pair), write the 16m x 32c fp16
        // tile into per-wave LDS scratch, then each lane stores one 16B row
        // segment. All 32 cols of a pair belong to ONE head's 32 dims.
        const float scale = 0.17677669529663687f;
        _Float16* sw = Alds + wid * 640;   // 16 rows x 34 f16 (+pad), per-wave
        const int row = lane >> 2;          // 0..15
        const int seg = lane & 3;           // 0..3
        #pragma unroll
        for (int fi = 0; fi < 4; ++fi) {
            #pragma unroll
            for (int fp = 0; fp < 2; ++fp) {       // fj pair (2fp, 2fp+1)
                #pragma unroll
                for (int ff = 0; ff < 2; ++ff) {
                    const int fj = fp * 2 + ff;
                    const int c = bn + wc * 64 + fj * 16 + lc;
                    const float bv = bias[c];
                    const float scl = ((c >> 8) == 0) ? scale : 1.0f;
                    #pragma unroll
                    for (int j = 0; j < 4; ++j)
                        sw[(lrb + j) * 34 + ff * 16 + lc] =
                            (_Float16)((acc[fi][fj][j] + bv) * scl);
                }
                const int c0 = bn + wc * 64 + fp * 32;
                const int which = c0 >> 8;          // 0=q 1=k 2=v
                const int head  = (c0 >> 5) & 7;
                _Float16* dst = (which == 0) ? qo : (which == 1) ? ko : vo;
                const int m = bm + wr * 64 + fi * 16 + row;
                f16x8 vv = *(const f16x8*)&sw[row * 34 + seg * 8];
                if (m < M)
                    *(f16x8*)&dst[((size_t)head * M + m) * HD + seg * 8] = vv;
            }
        }
    } else {
        #pragma unroll
        for (int fj = 0; fj < 4; ++fj) {
            const int c = bn + wc * 64 + fj * 16 + lc;
            const float bv = bias[c];
            #pragma unroll
            for (int fi = 0; fi < 4; ++fi) {
                #pragma unroll
                for (int j = 0; j < 4; ++j) {
                    const int m = bm + wr * 64 + fi * 16 + lrb + j;
                    if (m < M)
                        outf[(size_t)m * NB + c] = acc[fi][fj][j] + bv;
                }
            }
        }
    }
}

// ---------------------------------------------------------------------------
// Attention (round-4 verified kernel, 119 us): one query per thread,
// block = (head, 8h x 32w tile), single 34 KB LDS buffer time-shared K -> V.
// ---------------------------------------------------------------------------
#define KROWS 14
#define KCOLS 38
#define KUNITS (KROWS * KCOLS * 4)   // 2128 x 16B

__device__ __forceinline__ void stage_tile(const uint4* __restrict__ src,
                                           uint4* __restrict__ dst,
                                           int n, int r0, int w0, int tid)
{
    for (int u = tid; u < KUNITS; u += 256) {
        const int row = u / (KCOLS * 4);
        const int rem = u - row * (KCOLS * 4);
        const int col = rem >> 2;
        const int t   = rem & 3;
        int grow = r0 + row;
        if (grow > H_DIM - 1) grow = H_DIM - 1;   // clamped rows never read
        int gcol = w0 - 3 + col;
        if (gcol < 0) gcol += W_DIM;
        else if (gcol >= W_DIM) gcol -= W_DIM;
        dst[(row * KCOLS + col) * 4 + (t ^ ((col >> 1) & 3))] =
            src[(((size_t)n * H_DIM + grow) * W_DIM + gcol) * 4 + t];
    }
}

__device__ __forceinline__ float qkdot8(uint4 kk, const h2* qh, float acc)
{
    h2 k0 = __builtin_bit_cast(h2, kk.x);
    h2 k1 = __builtin_bit_cast(h2, kk.y);
    h2 k2 = __builtin_bit_cast(h2, kk.z);
    h2 k3 = __builtin_bit_cast(h2, kk.w);
#if HAS_FDOT2
    acc = __builtin_amdgcn_fdot2(k0, qh[0], acc, false);
    acc = __builtin_amdgcn_fdot2(k1, qh[1], acc, false);
    acc = __builtin_amdgcn_fdot2(k2, qh[2], acc, false);
    acc = __builtin_amdgcn_fdot2(k3, qh[3], acc, false);
#else
    acc += (float)k0.x * (float)qh[0].x + (float)k0.y * (float)qh[0].y;
    acc += (float)k1.x * (float)qh[1].x + (float)k1.y * (float)qh[1].y;
    acc += (float)k2.x * (float)qh[2].x + (float)k2.y * (float)qh[2].y;
    acc += (float)k3.x * (float)qh[3].x + (float)k3.y * (float)qh[3].y;
#endif
    return acc;
}

__global__ __launch_bounds__(256)
void natten_attn_kernel(const _Float16* __restrict__ q,   // [8][M][32]
                        const uint4* __restrict__ kb,
                        const uint4* __restrict__ vb,
                        const float* __restrict__ rpb,    // [8][13][13]
                        _Float16* __restrict__ outh)      // [M][256]
{
    __shared__ uint4 kvs[KUNITS];
    __shared__ float rpbs[169];

    const int tid = threadIdx.x;
    const int n  = blockIdx.z;
    const int w0 = blockIdx.x * 32;
    const int h0 = blockIdx.y * 8;

    int r0 = h0 - 3;
    if (r0 < 0) r0 = 0;
    if (r0 > H_DIM - 7) r0 = H_DIM - 7;

    if (tid < 169) rpbs[tid] = rpb[n * 169 + tid];

    // ---- phase 1: stage K ----
    stage_tile(kb, kvs, n, r0, w0, tid);
    __syncthreads();

    const int hl = tid >> 5;
    const int wl = tid & 31;
    const int h = h0 + hl;
    const int w = w0 + wl;
    const bool valid = (h < H_DIM) && (w < W_DIM);

    float sc[49];
    float inv = 0.f;
    int ri0 = 0;

    if (valid) {
        int sh = h - 3;
        if (sh < 0) sh = 0;
        if (sh > H_DIM - 7) sh = H_DIM - 7;
        ri0 = sh - r0;
        const int rh0 = sh - h + 6;

        // q (pre-scaled f16) kept packed: 16 half2 = 16 VGPRs
        const uint4* qp = reinterpret_cast<const uint4*>(
            q + ((size_t)n * MPIX + (size_t)h * W_DIM + w) * HD);
        h2 qh[16];
        #pragma unroll
        for (int t = 0; t < 4; ++t) {
            const uint4 qq = qp[t];
            qh[t*4+0] = __builtin_bit_cast(h2, qq.x);
            qh[t*4+1] = __builtin_bit_cast(h2, qq.y);
            qh[t*4+2] = __builtin_bit_cast(h2, qq.z);
            qh[t*4+3] = __builtin_bit_cast(h2, qq.w);
        }

        #pragma unroll
        for (int oi = 0; oi < 7; ++oi) {
            const int rb = (ri0 + oi) * (KCOLS * 4);
            #pragma unroll
            for (int oj = 0; oj < 7; ++oj) {
                const int cl = wl + oj;
                const int base = rb + cl * 4;
                const int sw = (cl >> 1) & 3;
                float dot = rpbs[(rh0 + oi) * 13 + 3 + oj];
                #pragma unroll
                for (int t = 0; t < 4; ++t)
                    dot = qkdot8(kvs[base + (t ^ sw)], qh + t * 4, dot);
                sc[oi * 7 + oj] = dot;
            }
        }

        float mx = sc[0];
        #pragma unroll
        for (int i = 1; i < 49; ++i) mx = fmaxf(mx, sc[i]);
        float ssum = 0.f;
        #pragma unroll
        for (int i = 0; i < 49; ++i) { sc[i] = __expf(sc[i] - mx); ssum += sc[i]; }
        inv = 1.f / ssum;
    }
    __syncthreads();

    // ---- phase 2: stage V into the same buffer ----
    stage_tile(vb, kvs, n, r0, w0, tid);
    __syncthreads();

    if (!valid) return;

    // PV: accumulate raw exp weights; normalize at the end.
    float acc[32];
    #pragma unroll
    for (int t = 0; t < 32; ++t) acc[t] = 0.f;
    #pragma unroll
    for (int oi = 0; oi < 7; ++oi) {
        const int rb = (ri0 + oi) * (KCOLS * 4);
        #pragma unroll
        for (int oj = 0; oj < 7; ++oj) {
            const int cl = wl + oj;
            const int base = rb + cl * 4;
            const int sw = (cl >> 1) & 3;
            const float a = sc[oi * 7 + oj];
            #pragma unroll
            for (int t = 0; t < 4; ++t) {
                const uint4 vv = kvs[base + (t ^ sw)];
                h2 v0 = __builtin_bit_cast(h2, vv.x);
                h2 v1 = __builtin_bit_cast(h2, vv.y);
                h2 v2 = __builtin_bit_cast(h2, vv.z);
                h2 v3 = __builtin_bit_cast(h2, vv.w);
                acc[t*8+0] += a * (float)v0.x; acc[t*8+1] += a * (float)v0.y;
                acc[t*8+2] += a * (float)v1.x; acc[t*8+3] += a * (float)v1.y;
                acc[t*8+4] += a * (float)v2.x; acc[t*8+5] += a * (float)v2.y;
                acc[t*8+6] += a * (float)v3.x; acc[t*8+7] += a * (float)v3.y;
            }
        }
    }

    uint4 o[4];
    #pragma unroll
    for (int t = 0; t < 4; ++t) {
        h2 p0 = { (_Float16)(acc[t*8+0] * inv), (_Float16)(acc[t*8+1] * inv) };
        h2 p1 = { (_Float16)(acc[t*8+2] * inv), (_Float16)(acc[t*8+3] * inv) };
        h2 p2 = { (_Float16)(acc[t*8+4] * inv), (_Float16)(acc[t*8+5] * inv) };
        h2 p3 = { (_Float16)(acc[t*8+6] * inv), (_Float16)(acc[t*8+7] * inv) };
        o[t].x = __builtin_bit_cast(unsigned, p0);
        o[t].y = __builtin_bit_cast(unsigned, p1);
        o[t].z = __builtin_bit_cast(unsigned, p2);
        o[t].w = __builtin_bit_cast(unsigned, p3);
    }
    uint4* op = reinterpret_cast<uint4*>(
        outh + (((size_t)h * W_DIM + w) * CH + n * HD));
    #pragma unroll
    for (int t = 0; t < 4; ++t) op[t] = o[t];
}

// ---------------------------------------------------------------------------
extern "C" void kernel_launch(void* const* d_in, const int* in_sizes, int n_in,
                              void* d_out, int out_size, void* d_ws, size_t ws_size,
                              hipStream_t stream)
{
    const float* x      = (const float*)d_in[0];
    const float* w_qkv  = (const float*)d_in[1];
    const float* b_qkv  = (const float*)d_in[2];
    const float* rpb    = (const float*)d_in[3];
    const float* w_proj = (const float*)d_in[4];
    const float* b_proj = (const float*)d_in[5];
    float* out = (float*)d_out;

    const int M = MPIX;
    const size_t nelem = (size_t)M * KDIM;

    _Float16* Xh  = (_Float16*)d_ws;
    _Float16* Wqt = Xh  + nelem;
    _Float16* Wpt = Wqt + 768 * 256;
    _Float16* qb  = Wpt + 256 * 256;
    _Float16* kb  = qb  + nelem;
    _Float16* vb  = kb  + nelem;
    _Float16* ah  = vb  + nelem;

    const size_t need = (5 * nelem + 768 * 256 + 256 * 256) * sizeof(_Float16);
    if (ws_size < need) return;

    dim3 blk(256);
    convert_kernel<<<dim3(8100, 3), blk, 0, stream>>>(x, w_qkv, w_proj, Xh, Wqt, Wpt);

    mfma_gemm_kernel<768, 0><<<dim3(6, 507), blk, 0, stream>>>(
        Xh, Wqt, b_qkv, qb, kb, vb, nullptr, M);

    natten_attn_kernel<<<dim3(12, 23, NHEAD), blk, 0, stream>>>(
        qb, (const uint4*)kb, (const uint4*)vb, rpb, ah);

    mfma_gemm_kernel<256, 1><<<dim3(2, 507), blk, 0, stream>>>(
        ah, Wpt, b_proj, nullptr, nullptr, nullptr, out, M);
}